// Round 1
// 278.706 us; speedup vs baseline: 1.3506x; 1.3506x over previous
//
#include <hip/hip_runtime.h>
#include <math.h>

typedef unsigned int uint;
typedef unsigned short ushort;
typedef short short8 __attribute__((ext_vector_type(8)));
typedef float f32x4 __attribute__((ext_vector_type(4)));

#define B_ 2048
#define N_ 256
#define D_ 64
#define ND_ 16384
#define NN_ 65536
#define KIDX_ 52428u
#define NGROUPS 16   // split-K over node groups for the fused gp partials

// ---------------- ws layout (bytes) ----------------
// node/final buffers are GONE: gp projection is folded into gpW1eff.
#define WS_W1T    ((size_t)0)                    // packed W1 B-frags bf16 : 2 MiB
#define WS_W2T    ((size_t)2*1024*1024)          // packed W2 B-frags bf16 : 2 MiB
#define WS_EFF    ((size_t)4*1024*1024)          // gpW1eff B-frags bf16 [256 nodes][4096] : 2 MiB
#define WS_ADJT   ((size_t)6*1024*1024)          // adj^T A-frags bf16 : 128 KiB
#define WS_GPARTS ((size_t)8*1024*1024)          // f32 [16][2048][64] : 8 MiB
#define WS_SCAL   ((size_t)16*1024*1024)

__device__ __forceinline__ ushort f2bf(float f) {
    uint u = __float_as_uint(f);
    u += 0x7fffu + ((u >> 16) & 1u);
    return (ushort)(u >> 16);
}
__device__ __forceinline__ float bf2f(ushort u) { return __uint_as_float(((uint)u) << 16); }

// exact float sigmoid via correctly-rounded double exp (matches numpy; verified R1-R4)
__device__ __forceinline__ float sigmoid_exact(float a) {
    float t = (float)exp(-(double)a);
    return 1.0f / (1.0f + t);
}

// B-fragment offset for 16x16x32 bf16: element (e=outcol, k) of a 64x64 W-slice.
// frag addr = (((nt*2+ks)*4+quad)*16+l16)*8 + pos ; nt=e>>4,l16=e&15, ks=k>>5,quad=(k>>3)&3,pos=k&7
__device__ __forceinline__ int wfrag_off(int e, int k) {
    return ((((e >> 4) * 2 + (k >> 5)) * 4 + ((k >> 3) & 3)) * 16 + (e & 15)) * 8 + (k & 7);
}

// ---------------- weight convert: pack W1/W2 in B-frag order ----------------
__global__ __launch_bounds__(256) void k_convert(const float* __restrict__ W1,
                                                 const float* __restrict__ W2,
                                                 ushort* __restrict__ W1f,
                                                 ushort* __restrict__ W2f) {
    int bid = blockIdx.x, tid = threadIdx.x;
    __shared__ ushort P[4096] __attribute__((aligned(16)));
    const float* src = (bid < 256) ? W1 + (size_t)bid * 4096 : W2 + (size_t)(bid - 256) * 4096;
#pragma unroll
    for (int i = 0; i < 16; i++) {
        int idx = i * 256 + tid;
        int k = idx >> 6, e = idx & 63;   // src is [k][e]
        P[wfrag_off(e, k)] = f2bf(src[idx]);
    }
    __syncthreads();
    ushort* dst = (bid < 256) ? W1f + (size_t)bid * 4096 : W2f + (size_t)(bid - 256) * 4096;
#pragma unroll
    for (int i = 0; i < 2; i++)
        ((uint4*)dst)[i * 256 + tid] = ((const uint4*)P)[i * 256 + tid];
}

// ---------------- exact rank select in PARAM space ----------------
// Serial tid==0 bin scan replaced by wave-parallel prefix scan (same arithmetic).
__global__ __launch_bounds__(1024, 4) void k_radix_select(const float* __restrict__ adj_param,
                                                          uint* __restrict__ scal) {
    __shared__ uint histL[256 * 64];   // [bin][lane] : 64 KiB, 2 lanes/bank (free)
    __shared__ uint wsum[4];
    __shared__ uint bc[2];
    int tid = threadIdx.x;
    int lane = tid & 63;
    uint prefix = 0;
    uint rank = KIDX_;
    const uint4* pv = (const uint4*)adj_param;
#pragma unroll 1
    for (int pass = 0; pass < 4; pass++) {
        int shift = 24 - 8 * pass;
        for (int i = tid; i < 256 * 64; i += 1024) histL[i] = 0u;
        __syncthreads();
#pragma unroll 1
        for (int i = 0; i < 16; i++) {
            uint4 b4 = pv[i * 1024 + tid];
#pragma unroll
            for (int c = 0; c < 4; c++) {
                uint bits = (c == 0) ? b4.x : (c == 1) ? b4.y : (c == 2) ? b4.z : b4.w;
                uint key = bits ^ ((bits & 0x80000000u) ? 0xFFFFFFFFu : 0x80000000u);
                bool cand = (pass == 0) || ((key >> (32 - 8 * pass)) == prefix);
                if (cand) atomicAdd(&histL[(((key >> shift) & 0xffu) << 6) + lane], 1u);
            }
        }
        __syncthreads();
        uint s0 = 0, sc = 0;
        if (tid < 256) {
            // per-bin reduction over 64 lanes (rotated to spread banks)
#pragma unroll
            for (int l = 0; l < 64; l++) s0 += histL[(tid << 6) + ((l + tid) & 63)];
            // inclusive prefix scan over bins: in-wave shfl scan + wave offsets
            sc = s0;
#pragma unroll
            for (int o = 1; o < 64; o <<= 1) {
                uint t = __shfl_up(sc, o, 64);
                if ((tid & 63) >= o) sc += t;
            }
            if ((tid & 63) == 63) wsum[tid >> 6] = sc;
        }
        __syncthreads();
        if (tid < 256) {
            uint base = 0;
#pragma unroll
            for (int w = 0; w < 4; w++)
                if (w < (tid >> 6)) base += wsum[w];
            uint incl = base + sc;
            uint excl = incl - s0;
            if (excl <= rank && rank < incl) {
                bc[0] = (prefix << 8) | (uint)tid;
                bc[1] = rank - excl;
            }
        }
        __syncthreads();
        prefix = bc[0];
        rank = bc[1];
        __syncthreads();
    }
    if (tid == 0) {
        uint key = prefix;
        uint bits = (key & 0x80000000u) ? (key ^ 0x80000000u) : ~key;
        scal[0] = __float_as_uint(sigmoid_exact(__uint_as_float(bits)));
    }
}

// ---------------- sigmoid + threshold + zero-diag; write adj fp32 + adj^T A-frag ------
__global__ __launch_bounds__(256) void k_thresh(const float* __restrict__ adj_param,
                                                const uint* __restrict__ scal,
                                                float* __restrict__ adj_out,
                                                ushort* __restrict__ adjTF) {
    int i = blockIdx.x * 256 + threadIdx.x;
    float thr = __uint_as_float(scal[0]);
    float s = sigmoid_exact(adj_param[i]);
    int r = i >> 8, c = i & 255;         // adj[r][c]
    float v = (s > thr && r != c) ? s : 0.0f;
    adj_out[i] = v;
    // adj^T A-frag: m = c (j), k = r (i)
    uint chunk = ((((uint)(c >> 4) * 8u + (uint)(r >> 5)) * 4u + (uint)((r >> 3) & 3)) * 16u + (uint)(c & 15));
    adjTF[chunk * 8u + (uint)(r & 7)] = f2bf(v);
}

// ---------------- gpW1eff: eff[j,d,e] = 0.5*gpW1[(j,d),e] + 0.5*sum_i adj[i,j]*gpW1[(i,d),e]
// GEMM per block: fixed d, 64 j x 64 e, K=256 (i). Output in B-frag order (k-dim = d).
__global__ __launch_bounds__(256) void k_eff(const float* __restrict__ gpW1,
                                             const ushort* __restrict__ adjTF,
                                             ushort* __restrict__ effF) {
    __shared__ ushort Bf[16384] __attribute__((aligned(16)));   // 4 k-slabs x 4096 frags, 32 KiB
    int d = blockIdx.x, jt = blockIdx.y, tid = threadIdx.x;
    // stage B[k=i][n=e] = gpW1[(i*64+d)*64+e] as bf16 frags
#pragma unroll
    for (int t = 0; t < 16; t++) {
        int idx = t * 256 + tid;        // 0..4095
        int i = idx >> 4;               // row 0..255
        int f4 = idx & 15;
        float4 v = *(const float4*)(gpW1 + ((size_t)i * 64 + d) * 64 + f4 * 4);
        int slab = i >> 6, il = i & 63, e0 = f4 * 4;
        Bf[slab * 4096 + wfrag_off(e0 + 0, il)] = f2bf(v.x);
        Bf[slab * 4096 + wfrag_off(e0 + 1, il)] = f2bf(v.y);
        Bf[slab * 4096 + wfrag_off(e0 + 2, il)] = f2bf(v.z);
        Bf[slab * 4096 + wfrag_off(e0 + 3, il)] = f2bf(v.w);
    }
    __syncthreads();
    int wid = tid >> 6, lane = tid & 63, quad = lane >> 4, l16 = lane & 15;
    f32x4 acc[4];
#pragma unroll
    for (int nt = 0; nt < 4; nt++) acc[nt] = (f32x4){0.f, 0.f, 0.f, 0.f};
#pragma unroll
    for (int ks8 = 0; ks8 < 8; ks8++) {
        short8 af = *(const short8*)&adjTF[(size_t)(((((jt * 4 + wid) * 8 + ks8) * 4 + quad) * 16 + l16)) * 8];
        int slab = ks8 >> 1, ks = ks8 & 1;
#pragma unroll
        for (int nt = 0; nt < 4; nt++) {
            short8 bf = *(const short8*)&Bf[slab * 4096 + (((nt * 2 + ks) * 4 + quad) * 16 + l16) * 8];
            acc[nt] = __builtin_amdgcn_mfma_f32_16x16x32_bf16(af, bf, acc[nt], 0, 0, 0);
        }
    }
#pragma unroll
    for (int nt = 0; nt < 4; nt++) {
        int e = nt * 16 + l16;
#pragma unroll
        for (int r = 0; r < 4; r++) {
            int j = jt * 64 + wid * 16 + quad * 4 + r;
            float w = gpW1[((size_t)j * 64 + d) * 64 + e];
            float eff = 0.5f * (acc[nt][r] + w);
            effF[(size_t)j * 4096 + wfrag_off(e, d)] = f2bf(eff);
        }
    }
}

// ---------------- fused: per-node 2-layer MLP + gp projection, node never hits HBM ----
// Block = (node-group g of 16 nodes, batch-tile of 64 rows); 4 waves x 16 rows each.
// Per node: stage W1f/W2f/effF (24 KiB) -> MLP layer1 -> St -> layer2 -> St ->
// gp GEMM (node-tile x gpW1eff[n]) accumulating into fp32 registers across the group.
__global__ __launch_bounds__(256, 3) void k_fused(const float* __restrict__ x,
                                                  const ushort* __restrict__ W1f,
                                                  const ushort* __restrict__ W2f,
                                                  const ushort* __restrict__ effF,
                                                  const float* __restrict__ b1,
                                                  const float* __restrict__ b2,
                                                  float* __restrict__ gparts) {
    __shared__ ushort Wf1[4096] __attribute__((aligned(16)));
    __shared__ ushort Wf2[4096] __attribute__((aligned(16)));
    __shared__ ushort Ef[4096] __attribute__((aligned(16)));
    __shared__ float Xs[4][16 * 68];     // per-wave x tile (stride 68 floats)
    __shared__ ushort St[4][16 * 72];    // per-wave h/node staging (stride 72 ushorts)
    int tid = threadIdx.x;
    int g = blockIdx.x, bt = blockIdx.y;
    int wid = tid >> 6, lane = tid & 63, quad = lane >> 4, l16 = lane & 15;
    int rbase = bt * 64 + wid * 16;
    float* Xw = &Xs[wid][0];
    ushort* Sw = &St[wid][0];

    f32x4 accg[4];
#pragma unroll
    for (int nt = 0; nt < 4; nt++) accg[nt] = (f32x4){0.f, 0.f, 0.f, 0.f};

#pragma unroll 1
    for (int nl = 0; nl < 16; nl++) {
        int n = g * 16 + nl;
        if (nl) __syncthreads();   // WAR: all waves done reading prev node's weights
        {
            const uint4* w1v = (const uint4*)(W1f + (size_t)n * 4096);
            const uint4* w2v = (const uint4*)(W2f + (size_t)n * 4096);
            const uint4* efv = (const uint4*)(effF + (size_t)n * 4096);
            ((uint4*)Wf1)[tid] = w1v[tid];
            ((uint4*)Wf1)[256 + tid] = w1v[256 + tid];
            ((uint4*)Wf2)[tid] = w2v[tid];
            ((uint4*)Wf2)[256 + tid] = w2v[256 + tid];
            ((uint4*)Ef)[tid] = efv[tid];
            ((uint4*)Ef)[256 + tid] = efv[256 + tid];
        }
        float bias1[4], bias2[4];
#pragma unroll
        for (int nt = 0; nt < 4; nt++) {
            bias1[nt] = b1[n * 64 + nt * 16 + l16];
            bias2[nt] = b2[n * 64 + nt * 16 + l16];
        }
        __syncthreads();           // RAW: weights visible

        // stage x tile (per-wave region, no cross-wave hazard): 16 rows x 256B
#pragma unroll
        for (int i = 0; i < 4; i++) {
            int idx = i * 64 + lane;
            int rl = idx >> 4, seg = idx & 15;
            *(float4*)&Xw[rl * 68 + seg * 4] =
                *(const float4*)(x + (size_t)(rbase + rl) * ND_ + n * 64 + seg * 4);
        }
        // A-frags (per-wave DS in-order; no barrier)
        short8 fa[2];
        int xr = l16 * 68;
#pragma unroll
        for (int ks = 0; ks < 2; ks++) {
            float4 A = *(const float4*)&Xw[xr + ks * 32 + quad * 8];
            float4 Bq = *(const float4*)&Xw[xr + ks * 32 + quad * 8 + 4];
            short8 a;
            a[0] = (short)f2bf(A.x); a[1] = (short)f2bf(A.y);
            a[2] = (short)f2bf(A.z); a[3] = (short)f2bf(A.w);
            a[4] = (short)f2bf(Bq.x); a[5] = (short)f2bf(Bq.y);
            a[6] = (short)f2bf(Bq.z); a[7] = (short)f2bf(Bq.w);
            fa[ks] = a;
        }
        // layer 1
        f32x4 acc[4];
#pragma unroll
        for (int nt = 0; nt < 4; nt++) acc[nt] = (f32x4){0.f, 0.f, 0.f, 0.f};
#pragma unroll
        for (int ks = 0; ks < 2; ks++)
#pragma unroll
            for (int nt = 0; nt < 4; nt++) {
                short8 bf = *(const short8*)&Wf1[(((nt * 2 + ks) * 4 + quad) * 16 + l16) * 8];
                acc[nt] = __builtin_amdgcn_mfma_f32_16x16x32_bf16(fa[ks], bf, acc[nt], 0, 0, 0);
            }
#pragma unroll
        for (int nt = 0; nt < 4; nt++)
#pragma unroll
            for (int r = 0; r < 4; r++) {
                float h = fmaxf(acc[nt][r] + bias1[nt], 0.0f);
                Sw[(quad * 4 + r) * 72 + nt * 16 + l16] = f2bf(h);
            }
        // layer 2
        f32x4 acc2[4];
#pragma unroll
        for (int nt = 0; nt < 4; nt++) acc2[nt] = (f32x4){0.f, 0.f, 0.f, 0.f};
#pragma unroll
        for (int ks = 0; ks < 2; ks++) {
            short8 a2 = *(const short8*)&Sw[l16 * 72 + ks * 32 + quad * 8];
#pragma unroll
            for (int nt = 0; nt < 4; nt++) {
                short8 bf = *(const short8*)&Wf2[(((nt * 2 + ks) * 4 + quad) * 16 + l16) * 8];
                acc2[nt] = __builtin_amdgcn_mfma_f32_16x16x32_bf16(a2, bf, acc2[nt], 0, 0, 0);
            }
        }
        // node tile (bias2, no relu) -> St as bf16
#pragma unroll
        for (int nt = 0; nt < 4; nt++)
#pragma unroll
            for (int r = 0; r < 4; r++) {
                float v = acc2[nt][r] + bias2[nt];
                Sw[(quad * 4 + r) * 72 + nt * 16 + l16] = f2bf(v);
            }
        // gp projection: accg += node_tile[16 x 64d] * gpW1eff[n][64d x 64e]
#pragma unroll
        for (int ks = 0; ks < 2; ks++) {
            short8 a3 = *(const short8*)&Sw[l16 * 72 + ks * 32 + quad * 8];
#pragma unroll
            for (int nt = 0; nt < 4; nt++) {
                short8 bf = *(const short8*)&Ef[(((nt * 2 + ks) * 4 + quad) * 16 + l16) * 8];
                accg[nt] = __builtin_amdgcn_mfma_f32_16x16x32_bf16(a3, bf, accg[nt], 0, 0, 0);
            }
        }
    }
    // write fp32 partials for this node-group
    float* gp = gparts + ((size_t)g * B_ + bt * 64) * 64;
#pragma unroll
    for (int nt = 0; nt < 4; nt++)
#pragma unroll
        for (int r = 0; r < 4; r++) {
            int b_loc = wid * 16 + quad * 4 + r;
            int e = nt * 16 + l16;
            gp[b_loc * 64 + e] = accg[nt][r];
        }
}

// ---------------- reduce partials, bias+relu, gp2 (fp32) ----------------
__global__ __launch_bounds__(64) void k_gp2(const float* __restrict__ gparts,
                                            const float* __restrict__ gpb1,
                                            const float* __restrict__ gpW2,
                                            const float* __restrict__ gpb2,
                                            float* __restrict__ out) {
    __shared__ float gs[64];
    int b = blockIdx.x, e = threadIdx.x;
    float s = gpb1[e];
#pragma unroll
    for (int p = 0; p < NGROUPS; p++) s += gparts[((size_t)p * B_ + b) * 64 + e];
    gs[e] = fmaxf(s, 0.0f);
    __syncthreads();
    if (e < 32) {
        float a = gpb2[e];
#pragma unroll 8
        for (int k2 = 0; k2 < 64; k2++) a += gs[k2] * gpW2[k2 * 32 + e];
        out[(size_t)b * 32 + e] = a;
    }
}

extern "C" void kernel_launch(void* const* d_in, const int* in_sizes, int n_in,
                              void* d_out, int out_size, void* d_ws, size_t ws_size,
                              hipStream_t stream) {
    const float* x = (const float*)d_in[0];
    const float* adj_param = (const float*)d_in[1];
    const float* W1 = (const float*)d_in[2];
    const float* b1 = (const float*)d_in[3];
    const float* W2 = (const float*)d_in[4];
    const float* b2 = (const float*)d_in[5];
    const float* gpW1 = (const float*)d_in[6];
    const float* gpb1 = (const float*)d_in[7];
    const float* gpW2 = (const float*)d_in[8];
    const float* gpb2 = (const float*)d_in[9];

    float* out = (float*)d_out;                 // [2048*32]
    float* adj_out = (float*)d_out + NN_;       // [256*256]

    char* ws = (char*)d_ws;
    ushort* W1f = (ushort*)(ws + WS_W1T);
    ushort* W2f = (ushort*)(ws + WS_W2T);
    ushort* effF = (ushort*)(ws + WS_EFF);
    ushort* adjTF = (ushort*)(ws + WS_ADJT);
    float* gparts = (float*)(ws + WS_GPARTS);
    uint* scal = (uint*)(ws + WS_SCAL);

    k_convert<<<512, 256, 0, stream>>>(W1, W2, W1f, W2f);
    k_radix_select<<<1, 1024, 0, stream>>>(adj_param, scal);
    k_thresh<<<256, 256, 0, stream>>>(adj_param, scal, adj_out, adjTF);
    k_eff<<<dim3(64, 4), 256, 0, stream>>>(gpW1, adjTF, effF);
    k_fused<<<dim3(NGROUPS, 32), 256, 0, stream>>>(x, W1f, W2f, effF, b1, b2, gparts);
    k_gp2<<<2048, 64, 0, stream>>>(gparts, gpb1, gpW2, gpb2, out);
}